// Round 8
// baseline (433.795 us; speedup 1.0000x reference)
//
#include <hip/hip_runtime.h>
#include <stdint.h>

// Problem constants (Qwen3NextCrossAttention): B=64, T=8, D=512, S=512, NKV=4, G=2
#define NB 64
#define NT 8
#define ND 512
#define NS 512
#define NKV 4
#define BSLICE 32
#define NSLICE (NB / BSLICE)   // 2

typedef __attribute__((ext_vector_type(8))) short short8_t;           // MFMA A/B frag
typedef __attribute__((ext_vector_type(8))) unsigned short ushort8_t;
typedef __attribute__((ext_vector_type(4))) float f32x4;              // MFMA C/D frag

typedef const __attribute__((address_space(1))) void gas_void;
typedef __attribute__((address_space(3))) void las_void;

// ws byte offsets. Total ~34.2 MB (hspHi slot unused -> effective ~17 MB).
#define HSP_HI 0ull           // (unused -- presplit deleted; ssq8/htilde read raw hist)
#define WKH_B  16777216ull    // Wk hi bf16 [2048][512]
#define WVH_B  18874368ull    // Wv hi bf16 [2048][512]
#define WKT_B  20971520ull    // (unused)
#define THI_B  23068672ull    // target hi bf16 [512][512]
#define TLO_B  23592960ull
#define QWH_B  24117248ull    // Wq hi
#define QWL_B  24641536ull
// ---- zero region (contiguous, 917504 floats) ----
#define QP_B   25165824ull    // qhat fp32 [512][512] (atomic K-split output)
#define DOT_B  26214400ull    // dot fp32 [256 bn][2][512] (atomic from gemm_ssq8)
#define OUTF_B 27262976ull    // out fp32 [512 rows [n][b][g]][512]
#define SSQ_B  28311552ull    // ssq fp32 [256 bn][512]
// -------------------------------------------------
#define PBUF_B 28966912ull    // probs fp32 [256 bn][2][512]
#define QPF_B  31064064ull    // q'' perm fp32 [512 rows [n][b][g]][512]  (1 MB)
#define HH_B   33161216ull    // h~ hi bf16 [512 rows [n][b][g]][512]
#define HL_B   33685504ull
#define FLAG_B 34209792ull    // int[2]: dtype flag, mask mode
#define ZERO_CNT 917504

__device__ __forceinline__ float b2f(unsigned short u) {
    union { unsigned int i; float f; } x; x.i = ((unsigned int)u) << 16; return x.f;
}
__device__ __forceinline__ unsigned short f2b(float f) {
    union { float f; unsigned int i; } x; x.f = f;
    unsigned int i = x.i;
    unsigned int r = i + 0x7FFFu + ((i >> 16) & 1u);   // RNE
    return (unsigned short)(r >> 16);
}
__device__ __forceinline__ float in_elem(const void* p, long long i, int is_f32) {
    return is_f32 ? ((const float*)p)[i] : b2f(((const unsigned short*)p)[i]);
}
__device__ __forceinline__ void store_out(void* out, int is_f32, size_t idx, float v) {
    if (is_f32) ((float*)out)[idx] = v;
    else        ((unsigned short*)out)[idx] = f2b(v);
}

// ---------------------------------------------------------------------------
// scan_zero: block 0 = dtype detect, block 1 = mask layout detect,
// blocks 2.. = zero the fp32 accumulator region (qp, dot, outF, ssq).
// ---------------------------------------------------------------------------
__global__ __launch_bounds__(256) void scan_zero_kernel(const unsigned short* __restrict__ hraw,
                                                        const void* __restrict__ mraw,
                                                        int* __restrict__ flag,
                                                        float* __restrict__ zbase) {
    const int tid = threadIdx.x;
    const int bx = blockIdx.x;
    if (bx >= 2) {
        zbase[(size_t)(bx - 2) * 256 + tid] = 0.0f;
        return;
    }
    if (bx == 0) {
        __shared__ int cnt;
        if (tid == 0) cnt = 0;
        __syncthreads();
        int c = 0;
#pragma unroll
        for (int it = 0; it < 16; ++it) {
            unsigned int e = (hraw[tid + it * 256] >> 7) & 0xFFu;
            if (e >= 0xF0u) ++c;
        }
        if (c) atomicAdd(&cnt, c);
        __syncthreads();
        if (tid == 0) flag[0] = (cnt >= 8) ? 1 : 0;
    } else {
        __shared__ int s_bf16, s_f32, s_not01, s_oddnz;
        if (tid == 0) { s_bf16 = 0; s_f32 = 0; s_not01 = 0; s_oddnz = 0; }
        __syncthreads();
        const unsigned int* w32 = (const unsigned int*)mraw;
        int f_bf16 = 0, f_f32 = 0, f_not01 = 0, f_oddnz = 0;
#pragma unroll
        for (int it = 0; it < 32; ++it) {
            const int i = tid + it * 256;
            unsigned int w = w32[i];
            if (w == 0x00003F80u || w == 0x3F803F80u) f_bf16 = 1;
            if (w == 0x3F800000u) f_f32 = 1;
            if (w != 0u && w != 1u && w != 0x3F800000u) f_not01 = 1;
            if ((i & 1) && w != 0u) f_oddnz = 1;
        }
        if (f_bf16)  s_bf16 = 1;
        if (f_f32)   s_f32 = 1;
        if (f_not01) s_not01 = 1;
        if (f_oddnz) s_oddnz = 1;
        __syncthreads();
        if (tid == 0) {
            int mode;
            if (s_bf16)       mode = 3;
            else if (s_f32)   mode = 0;
            else if (s_not01) mode = 1;
            else if (s_oddnz) mode = 0;
            else              mode = 2;
            flag[1] = mode;
        }
    }
}

// ---------------------------------------------------------------------------
// Split helpers
// ---------------------------------------------------------------------------
__device__ __forceinline__ void split8(const void* src, long long i8, int is_f32,
                                       ushort8_t& h, ushort8_t& l) {
    if (is_f32) {
        const float* s = (const float*)src + i8;
        float4 a = *(const float4*)s;
        float4 b = *(const float4*)(s + 4);
        float v[8] = {a.x, a.y, a.z, a.w, b.x, b.y, b.z, b.w};
#pragma unroll
        for (int j = 0; j < 8; ++j) {
            unsigned short hh = f2b(v[j]);
            h[j] = hh;
            l[j] = f2b(v[j] - b2f(hh));
        }
    } else {
        h = *(const ushort8_t*)((const unsigned short*)src + i8);
#pragma unroll
        for (int j = 0; j < 8; ++j) l[j] = 0;
    }
}
__device__ __forceinline__ ushort8_t hi8(const void* src, long long i8, int is_f32) {
    ushort8_t h;
    if (is_f32) {
        const float* s = (const float*)src + i8;
        float4 a = *(const float4*)s;
        float4 b = *(const float4*)(s + 4);
        float v[8] = {a.x, a.y, a.z, a.w, b.x, b.y, b.z, b.w};
#pragma unroll
        for (int j = 0; j < 8; ++j) h[j] = f2b(v[j]);
    } else {
        h = *(const ushort8_t*)((const unsigned short*)src + i8);
    }
    return h;
}

// ---------------------------------------------------------------------------
// prep: blocks 0-127 target hi/lo, 128-255 Wq hi/lo, 256-767 Wk hi,
// 768-1279 Wv hi.
// ---------------------------------------------------------------------------
__global__ __launch_bounds__(256) void prep_kernel(const void* __restrict__ target,
                                                   const void* __restrict__ Wq,
                                                   const void* __restrict__ Wk,
                                                   const void* __restrict__ Wv,
                                                   unsigned short* __restrict__ tHi,
                                                   unsigned short* __restrict__ tLo,
                                                   unsigned short* __restrict__ qwHi,
                                                   unsigned short* __restrict__ qwLo,
                                                   unsigned short* __restrict__ wkHi,
                                                   unsigned short* __restrict__ wvHi,
                                                   const int* __restrict__ flag) {
    const int bx = blockIdx.x;
    const int tid = threadIdx.x;
    const int is_f32 = flag[0];
    if (bx < 128) {
        const long long i8 = ((long long)bx * 256 + tid) * 8;
        ushort8_t h, l;
        split8(target, i8, is_f32, h, l);
        *(ushort8_t*)(tHi + i8) = h;
        *(ushort8_t*)(tLo + i8) = l;
    } else if (bx < 256) {
        const long long i8 = ((long long)(bx - 128) * 256 + tid) * 8;
        ushort8_t h, l;
        split8(Wq, i8, is_f32, h, l);
        *(ushort8_t*)(qwHi + i8) = h;
        *(ushort8_t*)(qwLo + i8) = l;
    } else if (bx < 768) {
        const long long i8 = ((long long)(bx - 256) * 256 + tid) * 8;
        *(ushort8_t*)(wkHi + i8) = hi8(Wk, i8, is_f32);
    } else {
        const long long i8 = ((long long)(bx - 768) * 256 + tid) * 8;
        *(ushort8_t*)(wvHi + i8) = hi8(Wv, i8, is_f32);
    }
}

// ---------------------------------------------------------------------------
// MFMA tiles. C/D: col = lane&15, row = (lane>>4)*4 + reg (m89-verified).
// ---------------------------------------------------------------------------

// 2-pass (A hi+lo) x B hi, K range [ktBeg, ktEnd)
__device__ __forceinline__ void mfma2_tile(const unsigned short* __restrict__ Ah,
                                           const unsigned short* __restrict__ Al,
                                           const unsigned short* __restrict__ B,
                                           unsigned short* AsH, unsigned short* AsL,
                                           unsigned short* Bs,
                                           int m0, int n0, int tid,
                                           int ktBeg, int ktEnd,
                                           f32x4 acc[4][4]) {
    const int lane = tid & 63, wave = tid >> 6;
    const int wr = wave >> 1, wc = wave & 1;
    const int lr = lane & 15, lq = lane >> 4;
#pragma unroll
    for (int i = 0; i < 4; ++i)
#pragma unroll
        for (int j = 0; j < 4; ++j) acc[i][j] = (f32x4){0.f, 0.f, 0.f, 0.f};

    for (int kt = ktBeg; kt < ktEnd; ++kt) {
        const int k0 = kt << 5;
#pragma unroll
        for (int i = 0; i < 2; ++i) {
            const int c = i * 256 + tid;
            const size_t aoff = (size_t)(m0 + (c >> 2)) * 512 + (k0 + (c & 3) * 8);
            const size_t boff = (size_t)(n0 + (c >> 2)) * 512 + (k0 + (c & 3) * 8);
            __builtin_amdgcn_global_load_lds((gas_void*)(Ah + aoff), (las_void*)(AsH + c * 8), 16, 0, 0);
            __builtin_amdgcn_global_load_lds((gas_void*)(Al + aoff), (las_void*)(AsL + c * 8), 16, 0, 0);
            __builtin_amdgcn_global_load_lds((gas_void*)(B + boff), (las_void*)(Bs + c * 8), 16, 0, 0);
        }
        __syncthreads();
        short8_t aH[4], aL[4], bF[4];
#pragma unroll
        for (int t = 0; t < 4; ++t) {
            const int ao = (wr * 64 + t * 16 + lr) * 32 + lq * 8;
            aH[t] = *(const short8_t*)(AsH + ao);
            aL[t] = *(const short8_t*)(AsL + ao);
            bF[t] = *(const short8_t*)(Bs + (wc * 64 + t * 16 + lr) * 32 + lq * 8);
        }
#pragma unroll
        for (int ti = 0; ti < 4; ++ti)
#pragma unroll
            for (int tj = 0; tj < 4; ++tj)
                acc[ti][tj] = __builtin_amdgcn_mfma_f32_16x16x32_bf16(aH[ti], bF[tj], acc[ti][tj], 0, 0, 0);
#pragma unroll
        for (int ti = 0; ti < 4; ++ti)
#pragma unroll
            for (int tj = 0; tj < 4; ++tj)
                acc[ti][tj] = __builtin_amdgcn_mfma_f32_16x16x32_bf16(aL[ti], bF[tj], acc[ti][tj], 0, 0, 0);
        __syncthreads();
    }
}

// 3-pass, K range
__device__ __forceinline__ void mfma3_tile(const unsigned short* __restrict__ Ah,
                                           const unsigned short* __restrict__ Al,
                                           const unsigned short* __restrict__ Bh,
                                           const unsigned short* __restrict__ Bl,
                                           unsigned short* AsH, unsigned short* AsL,
                                           unsigned short* BsH, unsigned short* BsL,
                                           int m0, int n0, int tid,
                                           int ktBeg, int ktEnd,
                                           f32x4 acc[4][4]) {
    const int lane = tid & 63, wave = tid >> 6;
    const int wr = wave >> 1, wc = wave & 1;
    const int lr = lane & 15, lq = lane >> 4;
#pragma unroll
    for (int i = 0; i < 4; ++i)
#pragma unroll
        for (int j = 0; j < 4; ++j) acc[i][j] = (f32x4){0.f, 0.f, 0.f, 0.f};

    for (int kt = ktBeg; kt < ktEnd; ++kt) {
        const int k0 = kt << 5;
#pragma unroll
        for (int i = 0; i < 2; ++i) {
            const int c = i * 256 + tid;
            const size_t aoff = (size_t)(m0 + (c >> 2)) * 512 + (k0 + (c & 3) * 8);
            const size_t boff = (size_t)(n0 + (c >> 2)) * 512 + (k0 + (c & 3) * 8);
            __builtin_amdgcn_global_load_lds((gas_void*)(Ah + aoff), (las_void*)(AsH + c * 8), 16, 0, 0);
            __builtin_amdgcn_global_load_lds((gas_void*)(Al + aoff), (las_void*)(AsL + c * 8), 16, 0, 0);
            __builtin_amdgcn_global_load_lds((gas_void*)(Bh + boff), (las_void*)(BsH + c * 8), 16, 0, 0);
            __builtin_amdgcn_global_load_lds((gas_void*)(Bl + boff), (las_void*)(BsL + c * 8), 16, 0, 0);
        }
        __syncthreads();
        short8_t aH[4], aL[4], bH[4], bL[4];
#pragma unroll
        for (int t = 0; t < 4; ++t) {
            const int ao = (wr * 64 + t * 16 + lr) * 32 + lq * 8;
            const int bo = (wc * 64 + t * 16 + lr) * 32 + lq * 8;
            aH[t] = *(const short8_t*)(AsH + ao);
            aL[t] = *(const short8_t*)(AsL + ao);
            bH[t] = *(const short8_t*)(BsH + bo);
            bL[t] = *(const short8_t*)(BsL + bo);
        }
#pragma unroll
        for (int ti = 0; ti < 4; ++ti)
#pragma unroll
            for (int tj = 0; tj < 4; ++tj)
                acc[ti][tj] = __builtin_amdgcn_mfma_f32_16x16x32_bf16(aH[ti], bH[tj], acc[ti][tj], 0, 0, 0);
#pragma unroll
    for (int ti = 0; ti < 4; ++ti)
#pragma unroll
            for (int tj = 0; tj < 4; ++tj)
                acc[ti][tj] = __builtin_amdgcn_mfma_f32_16x16x32_bf16(aH[ti], bL[tj], acc[ti][tj], 0, 0, 0);
#pragma unroll
        for (int ti = 0; ti < 4; ++ti)
#pragma unroll
            for (int tj = 0; tj < 4; ++tj)
                acc[ti][tj] = __builtin_amdgcn_mfma_f32_16x16x32_bf16(aL[ti], bH[tj], acc[ti][tj], 0, 0, 0);
        __syncthreads();
    }
}

// ---------------------------------------------------------------------------
// q projection, K-split x4: atomicAdd into fp32 qp. Grid (4,4,4).
// ---------------------------------------------------------------------------
__global__ __launch_bounds__(256) void gemm3_ks(const unsigned short* __restrict__ Ah,
                                                const unsigned short* __restrict__ Al,
                                                const unsigned short* __restrict__ Bh,
                                                const unsigned short* __restrict__ Bl,
                                                float* __restrict__ C) {
    __shared__ __align__(16) unsigned short AsH[128 * 32];
    __shared__ __align__(16) unsigned short AsL[128 * 32];
    __shared__ __align__(16) unsigned short BsH[128 * 32];
    __shared__ __align__(16) unsigned short BsL[128 * 32];
    const int m0 = blockIdx.x * 128, n0 = blockIdx.y * 128;
    const int kt0 = blockIdx.z * 4;
    const int tid = threadIdx.x;
    f32x4 acc[4][4];
    mfma3_tile(Ah, Al, Bh, Bl, AsH, AsL, BsH, BsL, m0, n0, tid, kt0, kt0 + 4, acc);
    const int lane = tid & 63, wave = tid >> 6;
    const int wr = wave >> 1, wc = wave & 1;
    const int lr = lane & 15, lq = lane >> 4;
#pragma unroll
    for (int ti = 0; ti < 4; ++ti)
#pragma unroll
        for (int tj = 0; tj < 4; ++tj)
#pragma unroll
            for (int r = 0; r < 4; ++r) {
                const int row = m0 + wr * 64 + ti * 16 + lq * 4 + r;
                const int col = n0 + wc * 64 + tj * 16 + lr;
                atomicAdd(&C[(size_t)row * 512 + col], acc[ti][tj][r]);
            }
}

// q'' = rmsnorm(qhat)*(1+qnw)*(1+knw)*SCALE -> permuted fp32 (for dot epilogue).
__global__ __launch_bounds__(64) void rmsnorm_qperm(const float* __restrict__ q,
                                                    const void* __restrict__ qnw,
                                                    const void* __restrict__ knw,
                                                    float* __restrict__ qpF,
                                                    const int* __restrict__ flag) {
    const int row = blockIdx.x;            // b*8 + h
    const int lane = threadIdx.x;
    const int is_f32 = flag[0];
    const float* p = q + (size_t)row * ND + lane * 8;
    float v[8];
    float4 a = *(const float4*)p;
    float4 b4 = *(const float4*)(p + 4);
    v[0] = a.x; v[1] = a.y; v[2] = a.z; v[3] = a.w;
    v[4] = b4.x; v[5] = b4.y; v[6] = b4.z; v[7] = b4.w;
    float ssq = 0.f;
#pragma unroll
    for (int j = 0; j < 8; ++j) ssq = fmaf(v[j], v[j], ssq);
#pragma unroll
    for (int off = 1; off < 64; off <<= 1) ssq += __shfl_xor(ssq, off);
    float r = rsqrtf(ssq * (1.0f / ND) + 1e-6f);
    const float SCALE = 0.044194173824159216f;  // 512^-0.5
    const int b = row >> 3, h = row & 7;
    const int prow = (h >> 1) * 128 + b * 2 + (h & 1);
    float o[8];
#pragma unroll
    for (int j = 0; j < 8; ++j) {
        int e = lane * 8 + j;
        o[j] = v[j] * r * (1.0f + in_elem(qnw, e, is_f32)) * (1.0f + in_elem(knw, e, is_f32)) * SCALE;
    }
    float4* dst = (float4*)(qpF + (size_t)prow * 512 + lane * 8);
    dst[0] = (float4){o[0], o[1], o[2], o[3]};
    dst[1] = (float4){o[4], o[5], o[6], o[7]};
}

// ---------------------------------------------------------------------------
// K projection + scores -- 256x256x64 8-phase pipelined MFMA GEMM (two-barrier
// schedule) + fused ssq/dot epilogue via two-stage LDS reduction.
// PRESPLIT DELETED: A is reg-staged directly from raw hist (f32 -> f2b -> bf16
// ds_write; bf16 passthrough). B stays on global_load_lds (wkHi bf16).
// Stage coverage invariant (R7 bug: A-even(1) was never staged -> NaN):
//   prologue: A-even(0), A-odd(0), A-even(1) WRITTEN; A-odd(1) in regs;
//             B(0) both halves + B-even(1) staged & resident.
//   loop t:   P0 writes A-odd(t+1) (regs from prev P2/prologue), issues
//             A-even(t+2); P2 writes A-even(t+2), issues A-odd(t+2);
//             P1/P3 stage B-odd(t+1)/B-even(t+2) via global_load_lds.
// Boundary drain (through B-odd(t+1)): outstanding at P3 end =
//   A-even(t+2) + B-odd(t+1) + A-odd(t+2) + B-even(t+2) = 12 f32 / 8 bf16
//   -> vmcnt(6) / vmcnt(4). Tail t=6: vmcnt(0).
// Hazards: every ds_write is >=2 barriers after its region's readers drained
// (their SYNC_PRE lgkmcnt(0)); compiler's in-order waits cover reg-load->cvt.
// ---------------------------------------------------------------------------
#define SSQ8_ABUF(b) ((b) * 32768)
#define SSQ8_BBUF(b) (65536 + (b) * 32768)
#define EPI_STRIDE 136   // 128 + 8 pad; *4B = 544, 16B-aligned rows

// Issue A loads for rows r0,r1 of K-tile tt into reg set (F = float4[4], U = ushort8[2])
#define SSQA_ISSUE(r0, r1, tt, F, U)                                                      \
    do {                                                                                  \
        const size_t ke_ = (size_t)(tt) * 64 + ksw;                                       \
        if (is_f32) {                                                                     \
            F[0] = *(const float4*)(histF + (size_t)(mBase + (r0)) * 512 + ke_);          \
            F[1] = *(const float4*)(histF + (size_t)(mBase + (r0)) * 512 + ke_ + 4);      \
            F[2] = *(const float4*)(histF + (size_t)(mBase + (r1)) * 512 + ke_);          \
            F[3] = *(const float4*)(histF + (size_t)(mBase + (r1)) * 512 + ke_ + 4);      \
        } else {                                                                          \
            U[0] = *(const ushort8_t*)(histU + (size_t)(mBase + (r0)) * 512 + ke_);       \
            U[1] = *(const ushort8_t*)(histU + (size_t)(mBase + (r1)) * 512 + ke_);       \
        }                                                                                 \
    } while (0)

// Convert + ds_write rows r0,r1 into buffer bufOff (dest layout identical to old STAGE_A)
#define SSQA_WRITE(r0, r1, bufOff, F, U)                                                  \
    do {                                                                                  \
        ushort8_t w0_, w1_;                                                               \
        if (is_f32) {                                                                     \
            float v0_[8] = {F[0].x, F[0].y, F[0].z, F[0].w, F[1].x, F[1].y, F[1].z, F[1].w}; \
            float v1_[8] = {F[2].x, F[2].y, F[2].z, F[2].w, F[3].x, F[3].y, F[3].z, F[3].w}; \
            _Pragma("unroll")                                                             \
            for (int j_ = 0; j_ < 8; ++j_) { w0_[j_] = (short)f2b(v0_[j_]); w1_[j_] = (short)f2b(v1_[j_]); } \
        } else { w0_ = (ushort8_t)U[0]; w1_ = (ushort8_t)U[1]; }                          \
        *(ushort8_t*)(smem + (bufOff) + (r0) * 128 + k0 * 2) = w0_;                       \
        *(ushort8_t*)(smem + (bufOff) + (r1) * 128 + k0 * 2) = w1_;                       \
    } while (0)

#define SSQ8_STAGE_B(q, tt, bufOff)                                                       \
    do {                                                                                  \
        const int rcB0_ = bR + (q) * 32;                                                  \
        __builtin_amdgcn_global_load_lds(                                                 \
            (gas_void*)(W + (size_t)(nBase + rcB0_) * 512 + (tt) * 64 + ksw),             \
            (las_void*)(smem + (bufOff) + rcB0_ * 128 + k0 * 2), 16, 0, 0);               \
        const int rcB1_ = rcB0_ + 128;                                                    \
        __builtin_amdgcn_global_load_lds(                                                 \
            (gas_void*)(W + (size_t)(nBase + rcB1_) * 512 + (tt) * 64 + ksw),             \
            (las_void*)(smem + (bufOff) + rcB1_ * 128 + k0 * 2), 16, 0, 0);               \
    } while (0)

#define SSQ8_READ_A(qm, bufOff)                                                           \
    _Pragma("unroll")                                                                     \
    for (int m_ = 0; m_ < 4; ++m_) {                                                      \
        const int rc_ = wm * 128 + (qm) * 64 + m_ * 16 + lr;                              \
        af[m_][0] = *(const short8_t*)(smem + (bufOff) + rc_ * 128 + kb0);                \
        af[m_][1] = *(const short8_t*)(smem + (bufOff) + rc_ * 128 + kb1);                \
    }

// loads bf[nh*2 + 0..1]; nh=0 -> B-even cols (qn=0), nh=1 -> B-odd (qn=1)
#define SSQ8_READ_B2(nh, bufOff)                                                          \
    _Pragma("unroll")                                                                     \
    for (int n_ = 0; n_ < 2; ++n_) {                                                      \
        const int cc_ = wn * 64 + (nh) * 32 + n_ * 16 + lr;                               \
        bf[(nh) * 2 + n_][0] = *(const short8_t*)(smem + (bufOff) + cc_ * 128 + kb0);     \
        bf[(nh) * 2 + n_][1] = *(const short8_t*)(smem + (bufOff) + cc_ * 128 + kb1);     \
    }

#define SSQ8_MFMA_Q(qm, nh)                                                               \
    _Pragma("unroll")                                                                     \
    for (int m_ = 0; m_ < 4; ++m_)                                                        \
    _Pragma("unroll")                                                                     \
    for (int n_ = 0; n_ < 2; ++n_) {                                                      \
        acc[(qm) * 4 + m_][(nh) * 2 + n_] = __builtin_amdgcn_mfma_f32_16x16x32_bf16(      \
            af[m_][0], bf[(nh) * 2 + n_][0], acc[(qm) * 4 + m_][(nh) * 2 + n_], 0, 0, 0); \
        acc[(qm) * 4 + m_][(nh) * 2 + n_] = __builtin_amdgcn_mfma_f32_16x16x32_bf16(      \
            af[m_][1], bf[(nh) * 2 + n_][1], acc[(qm) * 4 + m_][(nh) * 2 + n_], 0, 0, 0); \
    }

#define SSQ8_SYNC_PRE()                                                                   \
    __builtin_amdgcn_s_barrier();                                                         \
    asm volatile("s_waitcnt lgkmcnt(0)" ::: "memory");                                    \
    __builtin_amdgcn_sched_barrier(0);                                                    \
    __builtin_amdgcn_s_setprio(1);

#define SSQ8_SYNC_POST()                                                                  \
    __builtin_amdgcn_s_setprio(0);                                                        \
    __builtin_amdgcn_s_barrier();

__global__ __launch_bounds__(512) void gemm_ssq8(const void* __restrict__ hist,
                                                 const unsigned short* __restrict__ W,
                                                 const float* __restrict__ qpF,
                                                 float* __restrict__ ssq,
                                                 float* __restrict__ dotb,
                                                 const int* __restrict__ flag,
                                                 int b0) {
    extern __shared__ char smem[];
    const int tid = threadIdx.x;
    const int lane = tid & 63, wave = tid >> 6;
    const int wm = wave >> 2, wn = wave & 3;      // 2 x 4 wave grid
    const int lr = lane & 15, lq = lane >> 4;
    const int mBase = blockIdx.x * 256;
    const int nBase = blockIdx.y * 256;
    const int is_f32 = flag[0];

    const size_t sliceOff = (size_t)b0 * 512 * 512;
    const float* histF = (const float*)hist + sliceOff;
    const unsigned short* histU = (const unsigned short*)hist + sliceOff;

    // staging precompute: thread covers 16B chunk (row rl0(+offsets), k k0)
    const int rl0 = tid >> 3;                  // 0..63
    const int k0 = (tid & 7) << 3;             // element offset of chunk in K
    const int ksw = k0 ^ ((rl0 & 7) << 3);     // pre-swizzled source k
    const int bR = (rl0 & 31) | ((rl0 >> 5) << 6);   // B region base col
    // A rows handled by this thread
    const int arE0 = rl0, arE1 = rl0 + 128;          // even half: rows [0,64) u [128,192)
    const int arO0 = rl0 + 64, arO1 = rl0 + 192;     // odd half:  rows [64,128) u [192,256)

    // read-side swizzled K byte offsets (swizzle const per lane: lr&7)
    const int kb0 = ((lq * 8) ^ ((lr & 7) << 3)) * 2;
    const int kb1 = ((32 + lq * 8) ^ ((lr & 7) << 3)) * 2;

    f32x4 acc[8][4];
#pragma unroll
    for (int i = 0; i < 8; ++i)
#pragma unroll
        for (int j = 0; j < 4; ++j) acc[i][j] = (f32x4){0.f, 0.f, 0.f, 0.f};

    float4 fE[4], fO[4];
    ushort8_t uE[2], uO[2];

    // prologue (R8 fix: A-even(1) staged): issue A(0) both halves, stage all
    // early B; write A(0); issue+write A-even(1) (compiler's wait drains all
    // earlier B stages too); issue A-odd(1) (stays in regs for t=0 P0).
    SSQA_ISSUE(arE0, arE1, 0, fE, uE);
    SSQA_ISSUE(arO0, arO1, 0, fO, uO);
    SSQ8_STAGE_B(0, 0, SSQ8_BBUF(0));
    SSQ8_STAGE_B(1, 0, SSQ8_BBUF(0));
    SSQ8_STAGE_B(0, 1, SSQ8_BBUF(1));               // B-even(1)
    SSQA_WRITE(arE0, arE1, SSQ8_ABUF(0), fE, uE);   // waits A-even(0)
    SSQA_WRITE(arO0, arO1, SSQ8_ABUF(0), fO, uO);   // waits A-odd(0)
    SSQA_ISSUE(arE0, arE1, 1, fE, uE);              // A-even(1)
    SSQA_WRITE(arE0, arE1, SSQ8_ABUF(1), fE, uE);   // waits it (+ all B stages)
    SSQA_ISSUE(arO0, arO1, 1, fO, uO);              // A-odd(1) -> t=0 P0
    asm volatile("s_waitcnt lgkmcnt(0)" ::: "memory");
    __builtin_amdgcn_sched_barrier(0);
    __builtin_amdgcn_s_barrier();

    short8_t af[4][2], bf[4][2];

#pragma unroll
    for (int t = 0; t < 8; ++t) {
        const int cur = t & 1, nxt = cur ^ 1;
        const int aC = SSQ8_ABUF(cur), bC = SSQ8_BBUF(cur);
        const int aN = SSQ8_ABUF(nxt), bN = SSQ8_BBUF(nxt);
        // ---- P0: quad (0, n01) | write A-odd(t+1) | issue A-even(t+2) ----
        SSQ8_READ_A(0, aC)
        SSQ8_READ_B2(0, bC)
        if (t < 7) SSQA_WRITE(arO0, arO1, aN, fO, uO);
        if (t < 6) SSQA_ISSUE(arE0, arE1, t + 2, fE, uE);
        SSQ8_SYNC_PRE()
        SSQ8_MFMA_Q(0, 0)
        SSQ8_SYNC_POST()
        // ---- P1: quad (0, n23) | stage B-odd(t+1) ----
        SSQ8_READ_B2(1, bC)
        if (t + 1 < 8) SSQ8_STAGE_B(1, t + 1, bN);
        SSQ8_SYNC_PRE()
        SSQ8_MFMA_Q(0, 1)
        SSQ8_SYNC_POST()
        // ---- P2: quad (1, n01) | write A-even(t+2) | issue A-odd(t+2) ----
        SSQ8_READ_A(1, aC)
        if (t < 6) { SSQA_WRITE(arE0, arE1, aC, fE, uE); SSQA_ISSUE(arO0, arO1, t + 2, fO, uO); }
        SSQ8_SYNC_PRE()
        SSQ8_MFMA_Q(1, 0)
        SSQ8_SYNC_POST()
        // ---- P3: quad (1, n23) | stage B-even(t+2) | boundary vmcnt ----
        if (t + 2 < 8) SSQ8_STAGE_B(0, t + 2, bC);
        __builtin_amdgcn_s_barrier();
        __builtin_amdgcn_sched_barrier(0);
        __builtin_amdgcn_s_setprio(1);
        SSQ8_MFMA_Q(1, 1)
        __builtin_amdgcn_s_setprio(0);
        if (t < 6) {
            if (is_f32) { asm volatile("s_waitcnt vmcnt(6)" ::: "memory"); }
            else        { asm volatile("s_waitcnt vmcnt(4)" ::: "memory"); }
        } else if (t == 6) {
            asm volatile("s_waitcnt vmcnt(0)" ::: "memory");
        }
        __builtin_amdgcn_s_barrier();
    }

    // ---- fused epilogue: two-stage LDS reduction ----
    const int nh = (int)(blockIdx.y >> 1);
    const int bG = b0 + (mBase >> 9);
    const int bn = bG * 4 + nh;
    const int sBase0 = mBase & 511;
    // q'' values for this thread's 4 e-cols, both g rows
    const int dBase = (nBase & 511) + wn * 64 + lr;
    const size_t qrow0 = (size_t)(nh * 128 + bG * 2) * 512;
    float qv0[4], qv1[4];
#pragma unroll
    for (int n = 0; n < 4; ++n) {
        qv0[n] = qpF[qrow0 + dBase + n * 16];
        qv1[n] = qpF[qrow0 + 512 + dBase + n * 16];
    }
    float* lv   = (float*)smem;                // [64 col][EPI_STRIDE]
    float* ld0  = lv  + 64 * EPI_STRIDE;
    float* ld1  = ld0 + 64 * EPI_STRIDE;       // 104448 B
    float* part = ld1 + 64 * EPI_STRIDE;       // [3][128][4] = 6144 B (total 110592 < 128K)
    const int col = wn * 16 + lr;

#pragma unroll
    for (int p = 0; p < 2; ++p) {
        __syncthreads();
#pragma unroll
        for (int mm = 0; mm < 4; ++mm) {
            const int m = p * 4 + mm;
            f32x4 vv, dd0, dd1;
#pragma unroll
            for (int r = 0; r < 4; ++r) {
                float v = 0.f, d0 = 0.f, d1 = 0.f;
#pragma unroll
                for (int n = 0; n < 4; ++n) {
                    float x = acc[m][n][r];
                    v = fmaf(x, x, v);
                    d0 = fmaf(x, qv0[n], d0);
                    d1 = fmaf(x, qv1[n], d1);
                }
                vv[r] = v; dd0[r] = d0; dd1[r] = d1;
            }
            const int idx = wm * 64 + mm * 16 + lq * 4;   // +r consecutive
            *(f32x4*)(lv  + col * EPI_STRIDE + idx) = vv;
            *(f32x4*)(ld0 + col * EPI_STRIDE + idx) = dd0;
            *(f32x4*)(ld1 + col * EPI_STRIDE + idx) = dd1;
        }
        __syncthreads();
        // stage 1: all 512 threads; (t = col chunk, i = s index); 16-col sums
        {
            const int t = tid >> 7, i = tid & 127;
            float s0 = 0.f, s1 = 0.f, s2 = 0.f;
#pragma unroll
            for (int c = 0; c < 16; ++c) {
                const int cc = t * 16 + c;
                s0 += lv [cc * EPI_STRIDE + i];
                s1 += ld0[cc * EPI_STRIDE + i];
                s2 += ld1[cc * EPI_STRIDE + i];
            }
            part[(0 * 128 + i) * 4 + t] = s0;
            part[(1 * 128 + i) * 4 + t] = s1;
            part[(2 * 128 + i) * 4 + t] = s2;
        }
        __syncthreads();
        // stage 2: 384 threads; f32x4 partial read + reduce + atomic
        if (tid < 384) {
            const int v = tid >> 7, i = tid & 127;
            f32x4 pp = *(const f32x4*)(part + ((size_t)v * 128 + i) * 4);
            float sum = (pp[0] + pp[1]) + (pp[2] + pp[3]);
            const int s = sBase0 + (i >> 6) * 128 + p * 64 + (i & 63);
            if (v == 0)      atomicAdd(&ssq[(size_t)bn * 512 + s], sum);
            else if (v == 1) atomicAdd(&dotb[((size_t)bn * 2 + 0) * 512 + s], sum);
            else             atomicAdd(&dotb[((size_t)bn * 2 + 1) * 512 + s], sum);
        }
    }
}

// ---------------------------------------------------------------------------
// Softmax per (b,n): score = rsqrt(ssq/512+eps)*dot. Mask read inline (raw),
// mode from flag[1].
// ---------------------------------------------------------------------------
__global__ __launch_bounds__(512) void softmax_slice(const float* __restrict__ ssq,
                                                     const float* __restrict__ dot,
                                                     const void* __restrict__ mraw,
                                                     float* __restrict__ pbuf,
                                                     void* __restrict__ out,
                                                     const int* __restrict__ flag,
                                                     int b0) {
    const int bn = b0 * 4 + blockIdx.x;
    const int b = bn >> 2;
    const int tid = threadIdx.x;          // = s
    const int wave = tid >> 6, lane = tid & 63;
    const int is_f32 = flag[0];
    const int mode = flag[1];
    __shared__ float red[32];

    float sq = ssq[(size_t)bn * 512 + tid];
    float rms = rsqrtf(sq * (1.0f / ND) + 1e-6f);
    const int mi = b * NS + tid;
    int masked;
    if (mode == 3)      masked = (((const unsigned short*)mraw)[mi] != 0);
    else if (mode == 1) masked = (((const unsigned char*)mraw)[mi] != 0);
    else if (mode == 0) masked = (((const unsigned int*)mraw)[mi] != 0u);
    else                masked = (((const unsigned int*)mraw)[2 * mi] != 0u);
    float ninf = -__builtin_inff();
    float v0 = masked ? ninf : dot[((size_t)bn * 2 + 0) * 512 + tid] * rms;
    float v1 = masked ? ninf : dot[((size_t)bn * 2 + 1) * 512 + tid] * rms;

    float m0 = v0, m1 = v1;
#pragma unroll
    for (int off = 1; off < 64; off <<= 1) {
        m0 = fmaxf(m0, __shfl_xor(m0, off));
        m1 = fmaxf(m1, __shfl_xor(m1, off));
    }
    if (lane == 0) { red[wave] = m0; red[8 + wave] = m1; }
    __syncthreads();
    m0 = red[0]; m1 = red[8];
#pragma unroll
    for (int w = 1; w < 8; ++w) { m0 = fmaxf(m0, red[w]); m1 = fmaxf(m1, red[8 + w]); }
    float e0 = __expf(v0 - m0), e1 = __expf(v1 - m1);
    float su0 = e0, su1 = e1;
#pragma unroll
    for (int off = 1; off < 64; off <<= 1) {
        su0 += __shfl_xor(su0, off);
        su1 += __shfl_xor(su1, off);
    }
    if (lane == 0) { red[16 + wave] = su0; red[24 + wave] = su1; }
    __syncthreads();
    float t0 = 0.f, t1 = 0.f;
#pragma unroll
    for (int w = 0; w < 8; ++w) { t0 += red[16 + w]; t1 += red[24 + w]; }
    float p0 = e0 / t0, p1 = e1 / t1;

    pbuf[((size_t)bn * 2 + 0) * 512 + tid] = p0;
    pbuf[((size_t)bn * 2 + 1) * 512 + tid] = p1;
    size_t abase = 262144u + (size_t)bn * 1024 + tid;
    store_out(out, is_f32, abase, p0);
    store_out(out, is_f32, abase + 512, p1);
}

// ---------------------------------------------------------------------------
// h~: Grid (BSLICE, 8 d-chunks), 512 threads. Reads RAW hist (f32 or bf16).
// Thread (dl, sl) accumulates 64 s-rows for one d; LDS reduce over 8 s-lanes.
// ---------------------------------------------------------------------------
__global__ __launch_bounds__(512) void htilde_kernel(const void* __restrict__ hist,
                                                     const float* __restrict__ pbuf,
                                                     unsigned short* __restrict__ hHi,
                                                     unsigned short* __restrict__ hLo,
                                                     const int* __restrict__ flag,
                                                     int b0) {
    __shared__ float pl[8][512];          // 16 KB probs
    __shared__ float red[8][64][8];       // 16 KB partials [slane][d][h]
    const int bl = blockIdx.x;
    const int bG = b0 + bl;
    const int d0 = blockIdx.y * 64;
    const int tid = threadIdx.x;
    const int is_f32 = flag[0];
#pragma unroll
    for (int k = 0; k < 8; ++k) {
        const int j = tid + k * 512;
        const int h = j >> 9, s = j & 511;
        pl[h][s] = pbuf[((size_t)(bG * 4 + (h >> 1)) * 2 + (h & 1)) * 512 + s];
    }
    __syncthreads();

    const int dl = tid & 63, sl = tid >> 6;
    const size_t hbase = (size_t)bG * 262144 + (size_t)(d0 + dl);
    float acc[8];
#pragma unroll
    for (int h = 0; h < 8; ++h) acc[h] = 0.f;
    if (is_f32) {
        const float* hF = (const float*)hist + hbase;
#pragma unroll 4
        for (int i = 0; i < 64; ++i) {
            const int s = i * 8 + sl;
            float hv = hF[(size_t)s * 512];
#pragma unroll
            for (int h = 0; h < 8; ++h) acc[h] = fmaf(pl[h][s], hv, acc[h]);
        }
    } else {
        const unsigned short* hU = (const unsigned short*)hist + hbase;
#pragma unroll 4
        for (int i = 0; i < 64; ++i) {
            const int s = i * 8 + sl;
            float hv = b2f(hU[(size_t)s * 512]);
#pragma unroll
            for (int h = 0; h < 8; ++h) acc[h] = fmaf(pl[h][s], hv, acc[h]);
        }
    }
#pragma unroll
    for (int h = 0; h < 8; ++h) red[sl][dl][h] = acc[h];
    __syncthreads();

    const int dl2 = tid >> 3, h2 = tid & 7;
    float v = 0.f;
#pragma unroll
    for (int s2 = 0; s2 < 8; ++s2) v += red[s2][dl2][h2];
    const int row = (h2 >> 1) * 128 + bG * 2 + (h2 & 1);
    unsigned short hv = f2b(v);
    hHi[(size_t)row * 512 + d0 + dl2] = hv;
    hLo[(size_t)row * 512 + d0 + dl2] = f2b(v - b2f(hv));
}

// gemm_out K-split: grid (4 n, 4 e-tiles, 4 k-chunks) -> atomicAdd fp32 outF.
__global__ __launch_bounds__(256) void gemm_out_ks(const unsigned short* __restrict__ hHi,
                                                   const unsigned short* __restrict__ hLo,
                                                   const unsigned short* __restrict__ wvHi,
                                                   float* __restrict__ outF) {
    __shared__ __align__(16) unsigned short AsH[128 * 32];
    __shared__ __align__(16) unsigned short AsL[128 * 32];
    __shared__ __align__(16) unsigned short Bs[128 * 32];
    const int n = blockIdx.x;
    const int m0 = n * 128, n0 = blockIdx.y * 128;
    const int kt0 = blockIdx.z * 4;
    const int tid = threadIdx.x;
    f32x4 acc[4][4];
    mfma2_tile(hHi, hLo, wvHi + (size_t)n * 512 * 512, AsH, AsL, Bs, m0, n0, tid, kt0, kt0 + 4, acc);

    const int lane = tid & 63, wave = tid >> 6;
    const int wr = wave >> 1, wc = wave & 1;
    const int lr = lane & 15, lq = lane >> 4;
#pragma unroll
    for (int ti = 0; ti < 4; ++ti)
#pragma unroll
        for (int tj = 0; tj < 4; ++tj)
#pragma unroll
            for (int r = 0; r < 4; ++r) {
                const int row = m0 + wr * 64 + ti * 16 + lq * 4 + r;   // n*128 + b*2+g
                const int e = n0 + wc * 64 + tj * 16 + lr;
                atomicAdd(&outF[(size_t)row * 512 + e], acc[ti][tj][r]);
            }
}

// outF rows [n][b*2+g] -> out_tokens rows (b*8+n*2+g)
__global__ __launch_bounds__(256) void out_final_kernel(const float* __restrict__ outF,
                                                        void* __restrict__ out,
                                                        const int* __restrict__ flag) {
    const size_t i = (size_t)blockIdx.x * 256 + threadIdx.x;   // grid 1024
    const int row = (int)(i >> 9), e = (int)(i & 511);
    const int n = row >> 7, rl = row & 127;
    const int b = rl >> 1, g = rl & 1;
    store_out(out, flag[0], (size_t)(b * 8 + n * 2 + g) * 512 + e, outF[i]);
}

// ---------------------------------------------------------------------------
extern "C" void kernel_launch(void* const* d_in, const int* in_sizes, int n_in,
                              void* d_out, int out_size, void* d_ws, size_t ws_size,
                              hipStream_t stream) {
    (void)in_sizes; (void)n_in; (void)out_size; (void)ws_size;
    const void* target = d_in[0];   // [64,8,512]
    const void* hist   = d_in[1];   // [64,512,512]
    const void* mraw   = d_in[2];   // [64,512] bool-ish
    const void* Wq     = d_in[3];   // [512,512]
    const void* Wk     = d_in[4];   // [2048,512]
    const void* Wv     = d_in[5];   // [2048,512]
    const void* qnw    = d_in[6];   // [512]
    const void* knw    = d_in[7];   // [512]

    char* w = (char*)d_ws;
    unsigned short* wkHi  = (unsigned short*)(w + WKH_B);
    unsigned short* wvHi  = (unsigned short*)(w + WVH_B);
    unsigned short* tHi   = (unsigned short*)(w + THI_B);
    unsigned short* tLo   = (unsigned short*)(w + TLO_B);
    unsigned short* qwHi  = (unsigned short*)(w + QWH_B);
    unsigned short* qwLo  = (unsigned short*)(w + QWL_B);
    float* qp    = (float*)(w + QP_B);
    float* dotb  = (float*)(w + DOT_B);
    float* outF  = (float*)(w + OUTF_B);
    float* ssq   = (float*)(w + SSQ_B);
    float* pbuf  = (float*)(w + PBUF_B);
    float* qpF   = (float*)(w + QPF_B);
    unsigned short* hHi  = (unsigned short*)(w + HH_B);
    unsigned short* hLo  = (unsigned short*)(w + HL_B);
    int* flag = (int*)(w + FLAG_B);

    static bool attr_set = false;
    if (!attr_set) {
        (void)hipFuncSetAttribute(reinterpret_cast<const void*>(&gemm_ssq8),
                                  hipFuncAttributeMaxDynamicSharedMemorySize, 131072);
        attr_set = true;
    }

    scan_zero_kernel<<<2 + ZERO_CNT / 256, 256, 0, stream>>>(
        (const unsigned short*)hist, mraw, flag, qp);
    prep_kernel<<<1280, 256, 0, stream>>>(target, Wq, Wk, Wv, tHi, tLo, qwHi, qwLo,
                                          wkHi, wvHi, flag);

    gemm3_ks<<<dim3(4, 4, 4), 256, 0, stream>>>(tHi, tLo, qwHi, qwLo, qp);
    rmsnorm_qperm<<<NB * NT, 64, 0, stream>>>(qp, qnw, knw, qpF, flag);

    for (int sl = 0; sl < NSLICE; ++sl) {
        const int b0 = sl * BSLICE;
        gemm_ssq8<<<dim3(64, 8), 512, 131072, stream>>>(hist, wkHi, qpF, ssq, dotb, flag, b0);
        softmax_slice<<<BSLICE * NKV, 512, 0, stream>>>(ssq, dotb, mraw, pbuf, d_out, flag, b0);
        htilde_kernel<<<dim3(BSLICE, 8), 512, 0, stream>>>(hist, pbuf, hHi, hLo, flag, b0);
    }
    gemm_out_ks<<<dim3(4, 4, 4), 256, 0, stream>>>(hHi, hLo, wvHi, outF);
    out_final_kernel<<<1024, 256, 0, stream>>>(outF, d_out, flag);
}

// Round 9
// 243.510 us; speedup vs baseline: 1.7814x; 1.7814x over previous
//
#include <hip/hip_runtime.h>
#include <stdint.h>

// Problem constants (Qwen3NextCrossAttention): B=64, T=8, D=512, S=512, NKV=4, G=2
#define NB 64
#define NT 8
#define ND 512
#define NS 512
#define NKV 4
#define BSLICE 32
#define NSLICE (NB / BSLICE)   // 2

typedef __attribute__((ext_vector_type(8))) short short8_t;           // MFMA A/B frag
typedef __attribute__((ext_vector_type(8))) unsigned short ushort8_t;
typedef __attribute__((ext_vector_type(4))) float f32x4;              // MFMA C/D frag

typedef const __attribute__((address_space(1))) void gas_void;
typedef __attribute__((address_space(3))) void las_void;

// ws byte offsets. Total ~34.2 MB.
#define HSP_HI 0ull           // hist-slice hi bf16 [16384][512]  (16.8 MB)
#define WKH_B  16777216ull    // Wk hi bf16 [2048][512]
#define WVH_B  18874368ull    // Wv hi bf16 [2048][512]
#define WKT_B  20971520ull    // (unused)
#define THI_B  23068672ull    // target hi bf16 [512][512]
#define TLO_B  23592960ull
#define QWH_B  24117248ull    // Wq hi
#define QWL_B  24641536ull
// ---- zero region (contiguous, 917504 floats) ----
#define QP_B   25165824ull    // qhat fp32 [512][512] (atomic K-split output)
#define DOT_B  26214400ull    // dot fp32 [256 bn][2][512] (atomic from gemm_ssq8)
#define OUTF_B 27262976ull    // out fp32 [512 rows [n][b][g]][512]
#define SSQ_B  28311552ull    // ssq fp32 [256 bn][512]
// -------------------------------------------------
#define PBUF_B 28966912ull    // probs fp32 [256 bn][2][512]
#define QPF_B  31064064ull    // q'' perm fp32 [512 rows [n][b][g]][512]  (1 MB)
#define HH_B   33161216ull    // h~ hi bf16 [512 rows [n][b][g]][512]
#define HL_B   33685504ull
#define FLAG_B 34209792ull    // int[2]: dtype flag, mask mode
#define ZERO_CNT 917504

__device__ __forceinline__ float b2f(unsigned short u) {
    union { unsigned int i; float f; } x; x.i = ((unsigned int)u) << 16; return x.f;
}
__device__ __forceinline__ unsigned short f2b(float f) {
    union { float f; unsigned int i; } x; x.f = f;
    unsigned int i = x.i;
    unsigned int r = i + 0x7FFFu + ((i >> 16) & 1u);   // RNE
    return (unsigned short)(r >> 16);
}
__device__ __forceinline__ float in_elem(const void* p, long long i, int is_f32) {
    return is_f32 ? ((const float*)p)[i] : b2f(((const unsigned short*)p)[i]);
}
__device__ __forceinline__ void store_out(void* out, int is_f32, size_t idx, float v) {
    if (is_f32) ((float*)out)[idx] = v;
    else        ((unsigned short*)out)[idx] = f2b(v);
}

// ---------------------------------------------------------------------------
// scan_zero: block 0 = dtype detect, block 1 = mask layout detect,
// blocks 2.. = zero the fp32 accumulator region (qp, dot, outF, ssq).
// ---------------------------------------------------------------------------
__global__ __launch_bounds__(256) void scan_zero_kernel(const unsigned short* __restrict__ hraw,
                                                        const void* __restrict__ mraw,
                                                        int* __restrict__ flag,
                                                        float* __restrict__ zbase) {
    const int tid = threadIdx.x;
    const int bx = blockIdx.x;
    if (bx >= 2) {
        zbase[(size_t)(bx - 2) * 256 + tid] = 0.0f;
        return;
    }
    if (bx == 0) {
        __shared__ int cnt;
        if (tid == 0) cnt = 0;
        __syncthreads();
        int c = 0;
#pragma unroll
        for (int it = 0; it < 16; ++it) {
            unsigned int e = (hraw[tid + it * 256] >> 7) & 0xFFu;
            if (e >= 0xF0u) ++c;
        }
        if (c) atomicAdd(&cnt, c);
        __syncthreads();
        if (tid == 0) flag[0] = (cnt >= 8) ? 1 : 0;
    } else {
        __shared__ int s_bf16, s_f32, s_not01, s_oddnz;
        if (tid == 0) { s_bf16 = 0; s_f32 = 0; s_not01 = 0; s_oddnz = 0; }
        __syncthreads();
        const unsigned int* w32 = (const unsigned int*)mraw;
        int f_bf16 = 0, f_f32 = 0, f_not01 = 0, f_oddnz = 0;
#pragma unroll
        for (int it = 0; it < 32; ++it) {
            const int i = tid + it * 256;
            unsigned int w = w32[i];
            if (w == 0x00003F80u || w == 0x3F803F80u) f_bf16 = 1;
            if (w == 0x3F800000u) f_f32 = 1;
            if (w != 0u && w != 1u && w != 0x3F800000u) f_not01 = 1;
            if ((i & 1) && w != 0u) f_oddnz = 1;
        }
        if (f_bf16)  s_bf16 = 1;
        if (f_f32)   s_f32 = 1;
        if (f_not01) s_not01 = 1;
        if (f_oddnz) s_oddnz = 1;
        __syncthreads();
        if (tid == 0) {
            int mode;
            if (s_bf16)       mode = 3;
            else if (s_f32)   mode = 0;
            else if (s_not01) mode = 1;
            else if (s_oddnz) mode = 0;
            else              mode = 2;
            flag[1] = mode;
        }
    }
}

// ---------------------------------------------------------------------------
// Split helpers
// ---------------------------------------------------------------------------
__device__ __forceinline__ void split8(const void* src, long long i8, int is_f32,
                                       ushort8_t& h, ushort8_t& l) {
    if (is_f32) {
        const float* s = (const float*)src + i8;
        float4 a = *(const float4*)s;
        float4 b = *(const float4*)(s + 4);
        float v[8] = {a.x, a.y, a.z, a.w, b.x, b.y, b.z, b.w};
#pragma unroll
        for (int j = 0; j < 8; ++j) {
            unsigned short hh = f2b(v[j]);
            h[j] = hh;
            l[j] = f2b(v[j] - b2f(hh));
        }
    } else {
        h = *(const ushort8_t*)((const unsigned short*)src + i8);
#pragma unroll
        for (int j = 0; j < 8; ++j) l[j] = 0;
    }
}
__device__ __forceinline__ ushort8_t hi8(const void* src, long long i8, int is_f32) {
    ushort8_t h;
    if (is_f32) {
        const float* s = (const float*)src + i8;
        float4 a = *(const float4*)s;
        float4 b = *(const float4*)(s + 4);
        float v[8] = {a.x, a.y, a.z, a.w, b.x, b.y, b.z, b.w};
#pragma unroll
        for (int j = 0; j < 8; ++j) h[j] = f2b(v[j]);
    } else {
        h = *(const ushort8_t*)((const unsigned short*)src + i8);
    }
    return h;
}

// ---------------------------------------------------------------------------
// prep: blocks 0-127 target hi/lo, 128-255 Wq hi/lo, 256-767 Wk hi,
// 768-1279 Wv hi.
// ---------------------------------------------------------------------------
__global__ __launch_bounds__(256) void prep_kernel(const void* __restrict__ target,
                                                   const void* __restrict__ Wq,
                                                   const void* __restrict__ Wk,
                                                   const void* __restrict__ Wv,
                                                   unsigned short* __restrict__ tHi,
                                                   unsigned short* __restrict__ tLo,
                                                   unsigned short* __restrict__ qwHi,
                                                   unsigned short* __restrict__ qwLo,
                                                   unsigned short* __restrict__ wkHi,
                                                   unsigned short* __restrict__ wvHi,
                                                   const int* __restrict__ flag) {
    const int bx = blockIdx.x;
    const int tid = threadIdx.x;
    const int is_f32 = flag[0];
    if (bx < 128) {
        const long long i8 = ((long long)bx * 256 + tid) * 8;
        ushort8_t h, l;
        split8(target, i8, is_f32, h, l);
        *(ushort8_t*)(tHi + i8) = h;
        *(ushort8_t*)(tLo + i8) = l;
    } else if (bx < 256) {
        const long long i8 = ((long long)(bx - 128) * 256 + tid) * 8;
        ushort8_t h, l;
        split8(Wq, i8, is_f32, h, l);
        *(ushort8_t*)(qwHi + i8) = h;
        *(ushort8_t*)(qwLo + i8) = l;
    } else if (bx < 768) {
        const long long i8 = ((long long)(bx - 256) * 256 + tid) * 8;
        *(ushort8_t*)(wkHi + i8) = hi8(Wk, i8, is_f32);
    } else {
        const long long i8 = ((long long)(bx - 768) * 256 + tid) * 8;
        *(ushort8_t*)(wvHi + i8) = hi8(Wv, i8, is_f32);
    }
}

// hist slice presplit (hi only)
__global__ __launch_bounds__(256) void presplit_hist_kernel(const void* __restrict__ src,
                                                            unsigned short* __restrict__ hi,
                                                            const int* __restrict__ flag,
                                                            long long elemOff) {
    const long long i8 = ((long long)blockIdx.x * 256 + threadIdx.x) * 8;
    *(ushort8_t*)(hi + i8) = hi8(src, elemOff + i8, flag[0]);
}

// ---------------------------------------------------------------------------
// MFMA tiles. C/D: col = lane&15, row = (lane>>4)*4 + reg (m89-verified).
// ---------------------------------------------------------------------------

// 2-pass (A hi+lo) x B hi, K range [ktBeg, ktEnd)
__device__ __forceinline__ void mfma2_tile(const unsigned short* __restrict__ Ah,
                                           const unsigned short* __restrict__ Al,
                                           const unsigned short* __restrict__ B,
                                           unsigned short* AsH, unsigned short* AsL,
                                           unsigned short* Bs,
                                           int m0, int n0, int tid,
                                           int ktBeg, int ktEnd,
                                           f32x4 acc[4][4]) {
    const int lane = tid & 63, wave = tid >> 6;
    const int wr = wave >> 1, wc = wave & 1;
    const int lr = lane & 15, lq = lane >> 4;
#pragma unroll
    for (int i = 0; i < 4; ++i)
#pragma unroll
        for (int j = 0; j < 4; ++j) acc[i][j] = (f32x4){0.f, 0.f, 0.f, 0.f};

    for (int kt = ktBeg; kt < ktEnd; ++kt) {
        const int k0 = kt << 5;
#pragma unroll
        for (int i = 0; i < 2; ++i) {
            const int c = i * 256 + tid;
            const size_t aoff = (size_t)(m0 + (c >> 2)) * 512 + (k0 + (c & 3) * 8);
            const size_t boff = (size_t)(n0 + (c >> 2)) * 512 + (k0 + (c & 3) * 8);
            __builtin_amdgcn_global_load_lds((gas_void*)(Ah + aoff), (las_void*)(AsH + c * 8), 16, 0, 0);
            __builtin_amdgcn_global_load_lds((gas_void*)(Al + aoff), (las_void*)(AsL + c * 8), 16, 0, 0);
            __builtin_amdgcn_global_load_lds((gas_void*)(B + boff), (las_void*)(Bs + c * 8), 16, 0, 0);
        }
        __syncthreads();
        short8_t aH[4], aL[4], bF[4];
#pragma unroll
        for (int t = 0; t < 4; ++t) {
            const int ao = (wr * 64 + t * 16 + lr) * 32 + lq * 8;
            aH[t] = *(const short8_t*)(AsH + ao);
            aL[t] = *(const short8_t*)(AsL + ao);
            bF[t] = *(const short8_t*)(Bs + (wc * 64 + t * 16 + lr) * 32 + lq * 8);
        }
#pragma unroll
        for (int ti = 0; ti < 4; ++ti)
#pragma unroll
            for (int tj = 0; tj < 4; ++tj)
                acc[ti][tj] = __builtin_amdgcn_mfma_f32_16x16x32_bf16(aH[ti], bF[tj], acc[ti][tj], 0, 0, 0);
#pragma unroll
        for (int ti = 0; ti < 4; ++ti)
#pragma unroll
            for (int tj = 0; tj < 4; ++tj)
                acc[ti][tj] = __builtin_amdgcn_mfma_f32_16x16x32_bf16(aL[ti], bF[tj], acc[ti][tj], 0, 0, 0);
        __syncthreads();
    }
}

// 3-pass, K range
__device__ __forceinline__ void mfma3_tile(const unsigned short* __restrict__ Ah,
                                           const unsigned short* __restrict__ Al,
                                           const unsigned short* __restrict__ Bh,
                                           const unsigned short* __restrict__ Bl,
                                           unsigned short* AsH, unsigned short* AsL,
                                           unsigned short* BsH, unsigned short* BsL,
                                           int m0, int n0, int tid,
                                           int ktBeg, int ktEnd,
                                           f32x4 acc[4][4]) {
    const int lane = tid & 63, wave = tid >> 6;
    const int wr = wave >> 1, wc = wave & 1;
    const int lr = lane & 15, lq = lane >> 4;
#pragma unroll
    for (int i = 0; i < 4; ++i)
#pragma unroll
        for (int j = 0; j < 4; ++j) acc[i][j] = (f32x4){0.f, 0.f, 0.f, 0.f};

    for (int kt = ktBeg; kt < ktEnd; ++kt) {
        const int k0 = kt << 5;
#pragma unroll
        for (int i = 0; i < 2; ++i) {
            const int c = i * 256 + tid;
            const size_t aoff = (size_t)(m0 + (c >> 2)) * 512 + (k0 + (c & 3) * 8);
            const size_t boff = (size_t)(n0 + (c >> 2)) * 512 + (k0 + (c & 3) * 8);
            __builtin_amdgcn_global_load_lds((gas_void*)(Ah + aoff), (las_void*)(AsH + c * 8), 16, 0, 0);
            __builtin_amdgcn_global_load_lds((gas_void*)(Al + aoff), (las_void*)(AsL + c * 8), 16, 0, 0);
            __builtin_amdgcn_global_load_lds((gas_void*)(Bh + boff), (las_void*)(BsH + c * 8), 16, 0, 0);
            __builtin_amdgcn_global_load_lds((gas_void*)(Bl + boff), (las_void*)(BsL + c * 8), 16, 0, 0);
        }
        __syncthreads();
        short8_t aH[4], aL[4], bH[4], bL[4];
#pragma unroll
        for (int t = 0; t < 4; ++t) {
            const int ao = (wr * 64 + t * 16 + lr) * 32 + lq * 8;
            const int bo = (wc * 64 + t * 16 + lr) * 32 + lq * 8;
            aH[t] = *(const short8_t*)(AsH + ao);
            aL[t] = *(const short8_t*)(AsL + ao);
            bH[t] = *(const short8_t*)(BsH + bo);
            bL[t] = *(const short8_t*)(BsL + bo);
        }
#pragma unroll
        for (int ti = 0; ti < 4; ++ti)
#pragma unroll
            for (int tj = 0; tj < 4; ++tj)
                acc[ti][tj] = __builtin_amdgcn_mfma_f32_16x16x32_bf16(aH[ti], bH[tj], acc[ti][tj], 0, 0, 0);
#pragma unroll
    for (int ti = 0; ti < 4; ++ti)
#pragma unroll
            for (int tj = 0; tj < 4; ++tj)
                acc[ti][tj] = __builtin_amdgcn_mfma_f32_16x16x32_bf16(aH[ti], bL[tj], acc[ti][tj], 0, 0, 0);
#pragma unroll
        for (int ti = 0; ti < 4; ++ti)
#pragma unroll
            for (int tj = 0; tj < 4; ++tj)
                acc[ti][tj] = __builtin_amdgcn_mfma_f32_16x16x32_bf16(aL[ti], bH[tj], acc[ti][tj], 0, 0, 0);
        __syncthreads();
    }
}

// ---------------------------------------------------------------------------
// q projection, K-split x4: atomicAdd into fp32 qp. Grid (4,4,4).
// ---------------------------------------------------------------------------
__global__ __launch_bounds__(256) void gemm3_ks(const unsigned short* __restrict__ Ah,
                                                const unsigned short* __restrict__ Al,
                                                const unsigned short* __restrict__ Bh,
                                                const unsigned short* __restrict__ Bl,
                                                float* __restrict__ C) {
    __shared__ __align__(16) unsigned short AsH[128 * 32];
    __shared__ __align__(16) unsigned short AsL[128 * 32];
    __shared__ __align__(16) unsigned short BsH[128 * 32];
    __shared__ __align__(16) unsigned short BsL[128 * 32];
    const int m0 = blockIdx.x * 128, n0 = blockIdx.y * 128;
    const int kt0 = blockIdx.z * 4;
    const int tid = threadIdx.x;
    f32x4 acc[4][4];
    mfma3_tile(Ah, Al, Bh, Bl, AsH, AsL, BsH, BsL, m0, n0, tid, kt0, kt0 + 4, acc);
    const int lane = tid & 63, wave = tid >> 6;
    const int wr = wave >> 1, wc = wave & 1;
    const int lr = lane & 15, lq = lane >> 4;
#pragma unroll
    for (int ti = 0; ti < 4; ++ti)
#pragma unroll
        for (int tj = 0; tj < 4; ++tj)
#pragma unroll
            for (int r = 0; r < 4; ++r) {
                const int row = m0 + wr * 64 + ti * 16 + lq * 4 + r;
                const int col = n0 + wc * 64 + tj * 16 + lr;
                atomicAdd(&C[(size_t)row * 512 + col], acc[ti][tj][r]);
            }
}

// q'' = rmsnorm(qhat)*(1+qnw)*(1+knw)*SCALE -> permuted fp32 (for dot epilogue).
__global__ __launch_bounds__(64) void rmsnorm_qperm(const float* __restrict__ q,
                                                    const void* __restrict__ qnw,
                                                    const void* __restrict__ knw,
                                                    float* __restrict__ qpF,
                                                    const int* __restrict__ flag) {
    const int row = blockIdx.x;            // b*8 + h
    const int lane = threadIdx.x;
    const int is_f32 = flag[0];
    const float* p = q + (size_t)row * ND + lane * 8;
    float v[8];
    float4 a = *(const float4*)p;
    float4 b4 = *(const float4*)(p + 4);
    v[0] = a.x; v[1] = a.y; v[2] = a.z; v[3] = a.w;
    v[4] = b4.x; v[5] = b4.y; v[6] = b4.z; v[7] = b4.w;
    float ssq = 0.f;
#pragma unroll
    for (int j = 0; j < 8; ++j) ssq = fmaf(v[j], v[j], ssq);
#pragma unroll
    for (int off = 1; off < 64; off <<= 1) ssq += __shfl_xor(ssq, off);
    float r = rsqrtf(ssq * (1.0f / ND) + 1e-6f);
    const float SCALE = 0.044194173824159216f;  // 512^-0.5
    const int b = row >> 3, h = row & 7;
    const int prow = (h >> 1) * 128 + b * 2 + (h & 1);
    float o[8];
#pragma unroll
    for (int j = 0; j < 8; ++j) {
        int e = lane * 8 + j;
        o[j] = v[j] * r * (1.0f + in_elem(qnw, e, is_f32)) * (1.0f + in_elem(knw, e, is_f32)) * SCALE;
    }
    float4* dst = (float4*)(qpF + (size_t)prow * 512 + lane * 8);
    dst[0] = (float4){o[0], o[1], o[2], o[3]};
    dst[1] = (float4){o[4], o[5], o[6], o[7]};
}

// ---------------------------------------------------------------------------
// K projection + scores -- 256x256x64 8-phase pipelined MFMA GEMM (two-barrier
// schedule) + fused ssq/dot epilogue via two-stage LDS reduction.
// Grid (64 mTiles, 8 nTiles), 512 threads (8 waves, 2M x 4N), 128 KiB dyn LDS.
// Each block owns one (batch bG, head nh); acc holds khat[s, e] fragments.
//   ssq[bn,s]    += sum_e khat^2
//   dot[bn,g,s]  += sum_e khat * q''[(nh,bG,g), e]
// Epilogue history: shfl trees = 120cy serialized swizzle chains (R4, ~41us);
// 64-deep scalar LDS read loop = lgkm-wait-bound under register pressure
// (R5, ~21us). Now: stage-1 = 512 threads x 16-col sums x 3 arrays (48
// conflict-free reads, 3 short chains, pipelines in-register), stage-2 = 384
// threads x {f32x4 partial read + 3 adds + 1 atomicAdd}.
// R8 lesson: reg-staging A from raw hist spills (acc 128 VGPR + 32 staging
// VGPR > budget -> 141MB scratch writes/dispatch). Presplit stays.
// ---------------------------------------------------------------------------
#define SSQ8_ABUF(b) ((b) * 32768)
#define SSQ8_BBUF(b) (65536 + (b) * 32768)
#define EPI_STRIDE 136   // 128 + 8 pad; *4B = 544, 16B-aligned rows

#define SSQ8_STAGE_A(r, tt, bufOff)                                                       \
    do {                                                                                  \
        const int rcA0_ = rl0 + (r) * 64;                                                 \
        __builtin_amdgcn_global_load_lds(                                                 \
            (gas_void*)(A + (size_t)(mBase + rcA0_) * 512 + (tt) * 64 + ksw),             \
            (las_void*)(smem + (bufOff) + rcA0_ * 128 + k0 * 2), 16, 0, 0);               \
        const int rcA1_ = rcA0_ + 128;                                                    \
        __builtin_amdgcn_global_load_lds(                                                 \
            (gas_void*)(A + (size_t)(mBase + rcA1_) * 512 + (tt) * 64 + ksw),             \
            (las_void*)(smem + (bufOff) + rcA1_ * 128 + k0 * 2), 16, 0, 0);               \
    } while (0)

#define SSQ8_STAGE_B(q, tt, bufOff)                                                       \
    do {                                                                                  \
        const int rcB0_ = bR + (q) * 32;                                                  \
        __builtin_amdgcn_global_load_lds(                                                 \
            (gas_void*)(W + (size_t)(nBase + rcB0_) * 512 + (tt) * 64 + ksw),             \
            (las_void*)(smem + (bufOff) + rcB0_ * 128 + k0 * 2), 16, 0, 0);               \
        const int rcB1_ = rcB0_ + 128;                                                    \
        __builtin_amdgcn_global_load_lds(                                                 \
            (gas_void*)(W + (size_t)(nBase + rcB1_) * 512 + (tt) * 64 + ksw),             \
            (las_void*)(smem + (bufOff) + rcB1_ * 128 + k0 * 2), 16, 0, 0);               \
    } while (0)

#define SSQ8_READ_A(qm, bufOff)                                                           \
    _Pragma("unroll")                                                                     \
    for (int m_ = 0; m_ < 4; ++m_) {                                                      \
        const int rc_ = wm * 128 + (qm) * 64 + m_ * 16 + lr;                              \
        af[m_][0] = *(const short8_t*)(smem + (bufOff) + rc_ * 128 + kb0);                \
        af[m_][1] = *(const short8_t*)(smem + (bufOff) + rc_ * 128 + kb1);                \
    }

// loads bf[nh*2 + 0..1]; nh=0 -> B-even cols (qn=0), nh=1 -> B-odd (qn=1)
#define SSQ8_READ_B2(nh, bufOff)                                                          \
    _Pragma("unroll")                                                                     \
    for (int n_ = 0; n_ < 2; ++n_) {                                                      \
        const int cc_ = wn * 64 + (nh) * 32 + n_ * 16 + lr;                               \
        bf[(nh) * 2 + n_][0] = *(const short8_t*)(smem + (bufOff) + cc_ * 128 + kb0);     \
        bf[(nh) * 2 + n_][1] = *(const short8_t*)(smem + (bufOff) + cc_ * 128 + kb1);     \
    }

#define SSQ8_MFMA_Q(qm, nh)                                                               \
    _Pragma("unroll")                                                                     \
    for (int m_ = 0; m_ < 4; ++m_)                                                        \
    _Pragma("unroll")                                                                     \
    for (int n_ = 0; n_ < 2; ++n_) {                                                      \
        acc[(qm) * 4 + m_][(nh) * 2 + n_] = __builtin_amdgcn_mfma_f32_16x16x32_bf16(      \
            af[m_][0], bf[(nh) * 2 + n_][0], acc[(qm) * 4 + m_][(nh) * 2 + n_], 0, 0, 0); \
        acc[(qm) * 4 + m_][(nh) * 2 + n_] = __builtin_amdgcn_mfma_f32_16x16x32_bf16(      \
            af[m_][1], bf[(nh) * 2 + n_][1], acc[(qm) * 4 + m_][(nh) * 2 + n_], 0, 0, 0); \
    }

#define SSQ8_SYNC_PRE()                                                                   \
    __builtin_amdgcn_s_barrier();                                                         \
    asm volatile("s_waitcnt lgkmcnt(0)" ::: "memory");                                    \
    __builtin_amdgcn_sched_barrier(0);                                                    \
    __builtin_amdgcn_s_setprio(1);

#define SSQ8_SYNC_POST()                                                                  \
    __builtin_amdgcn_s_setprio(0);                                                        \
    __builtin_amdgcn_s_barrier();

__global__ __launch_bounds__(512) void gemm_ssq8(const unsigned short* __restrict__ A,
                                                 const unsigned short* __restrict__ W,
                                                 const float* __restrict__ qpF,
                                                 float* __restrict__ ssq,
                                                 float* __restrict__ dotb,
                                                 int b0) {
    extern __shared__ char smem[];
    const int tid = threadIdx.x;
    const int lane = tid & 63, wave = tid >> 6;
    const int wm = wave >> 2, wn = wave & 3;      // 2 x 4 wave grid
    const int lr = lane & 15, lq = lane >> 4;
    const int mBase = blockIdx.x * 256;
    const int nBase = blockIdx.y * 256;

    // staging precompute: thread covers 16B chunk (row rl0(+offsets), k k0)
    const int rl0 = tid >> 3;                  // 0..63
    const int k0 = (tid & 7) << 3;             // element offset of chunk in K
    const int ksw = k0 ^ ((rl0 & 7) << 3);     // pre-swizzled source k
    const int bR = (rl0 & 31) | ((rl0 >> 5) << 6);   // B region base col

    // read-side swizzled K byte offsets (swizzle const per lane: lr&7)
    const int kb0 = ((lq * 8) ^ ((lr & 7) << 3)) * 2;
    const int kb1 = ((32 + lq * 8) ^ ((lr & 7) << 3)) * 2;

    f32x4 acc[8][4];
#pragma unroll
    for (int i = 0; i < 8; ++i)
#pragma unroll
        for (int j = 0; j < 4; ++j) acc[i][j] = (f32x4){0.f, 0.f, 0.f, 0.f};

    // prologue: A-even(0), B-even(0), A-odd(0), B-odd(0), A-even(1), B-even(1)
    SSQ8_STAGE_A(0, 0, SSQ8_ABUF(0));
    SSQ8_STAGE_B(0, 0, SSQ8_BBUF(0));
    SSQ8_STAGE_A(1, 0, SSQ8_ABUF(0));
    SSQ8_STAGE_B(1, 0, SSQ8_BBUF(0));
    SSQ8_STAGE_A(0, 1, SSQ8_ABUF(1));
    SSQ8_STAGE_B(0, 1, SSQ8_BBUF(1));
    asm volatile("s_waitcnt vmcnt(4)" ::: "memory");   // tile-0 regions resident
    __builtin_amdgcn_s_barrier();

    short8_t af[4][2], bf[4][2];

#pragma unroll
    for (int t = 0; t < 8; ++t) {
        const int cur = t & 1, nxt = cur ^ 1;
        const int aC = SSQ8_ABUF(cur), bC = SSQ8_BBUF(cur);
        const int aN = SSQ8_ABUF(nxt), bN = SSQ8_BBUF(nxt);
        // ---- P0: quad (0, n01) ----
        SSQ8_READ_A(0, aC)
        SSQ8_READ_B2(0, bC)
        if (t + 1 < 8) SSQ8_STAGE_A(1, t + 1, aN);
        SSQ8_SYNC_PRE()
        SSQ8_MFMA_Q(0, 0)
        SSQ8_SYNC_POST()
        // ---- P1: quad (0, n23) (A frags reused) ----
        SSQ8_READ_B2(1, bC)
        if (t + 1 < 8) SSQ8_STAGE_B(1, t + 1, bN);
        SSQ8_SYNC_PRE()
        SSQ8_MFMA_Q(0, 1)
        SSQ8_SYNC_POST()
        // ---- P2: quad (1, n01) (B frags in registers) ----
        SSQ8_READ_A(1, aC)
        if (t + 2 < 8) SSQ8_STAGE_A(0, t + 2, aC);
        SSQ8_SYNC_PRE()
        SSQ8_MFMA_Q(1, 0)
        SSQ8_SYNC_POST()
        // ---- P3: quad (1, n23) -- no ds_reads; barrier-pair kept ----
        if (t + 2 < 8) SSQ8_STAGE_B(0, t + 2, bC);
        __builtin_amdgcn_s_barrier();
        __builtin_amdgcn_sched_barrier(0);
        __builtin_amdgcn_s_setprio(1);
        SSQ8_MFMA_Q(1, 1)
        __builtin_amdgcn_s_setprio(0);
        if (t < 6) {
            asm volatile("s_waitcnt vmcnt(4)" ::: "memory");   // t+2 stages may fly
        } else if (t == 6) {
            asm volatile("s_waitcnt vmcnt(0)" ::: "memory");   // tail drain
        }
        __builtin_amdgcn_s_barrier();
    }

    // ---- fused epilogue: two-stage LDS reduction ----
    const int nh = (int)(blockIdx.y >> 1);
    const int bG = b0 + (mBase >> 9);
    const int bn = bG * 4 + nh;
    const int sBase0 = mBase & 511;
    // q'' values for this thread's 4 e-cols, both g rows
    const int dBase = (nBase & 511) + wn * 64 + lr;
    const size_t qrow0 = (size_t)(nh * 128 + bG * 2) * 512;
    float qv0[4], qv1[4];
#pragma unroll
    for (int n = 0; n < 4; ++n) {
        qv0[n] = qpF[qrow0 + dBase + n * 16];
        qv1[n] = qpF[qrow0 + 512 + dBase + n * 16];
    }
    float* lv   = (float*)smem;                // [64 col][EPI_STRIDE]
    float* ld0  = lv  + 64 * EPI_STRIDE;
    float* ld1  = ld0 + 64 * EPI_STRIDE;       // 104448 B
    float* part = ld1 + 64 * EPI_STRIDE;       // [3][128][4] = 6144 B (total 110592 < 128K)
    const int col = wn * 16 + lr;

#pragma unroll
    for (int p = 0; p < 2; ++p) {
        __syncthreads();
#pragma unroll
        for (int mm = 0; mm < 4; ++mm) {
            const int m = p * 4 + mm;
            f32x4 vv, dd0, dd1;
#pragma unroll
            for (int r = 0; r < 4; ++r) {
                float v = 0.f, d0 = 0.f, d1 = 0.f;
#pragma unroll
                for (int n = 0; n < 4; ++n) {
                    float x = acc[m][n][r];
                    v = fmaf(x, x, v);
                    d0 = fmaf(x, qv0[n], d0);
                    d1 = fmaf(x, qv1[n], d1);
                }
                vv[r] = v; dd0[r] = d0; dd1[r] = d1;
            }
            const int idx = wm * 64 + mm * 16 + lq * 4;   // +r consecutive
            *(f32x4*)(lv  + col * EPI_STRIDE + idx) = vv;
            *(f32x4*)(ld0 + col * EPI_STRIDE + idx) = dd0;
            *(f32x4*)(ld1 + col * EPI_STRIDE + idx) = dd1;
        }
        __syncthreads();
        // stage 1: all 512 threads; (t = col chunk, i = s index); 16-col sums
        {
            const int t = tid >> 7, i = tid & 127;
            float s0 = 0.f, s1 = 0.f, s2 = 0.f;
#pragma unroll
            for (int c = 0; c < 16; ++c) {
                const int cc = t * 16 + c;
                s0 += lv [cc * EPI_STRIDE + i];
                s1 += ld0[cc * EPI_STRIDE + i];
                s2 += ld1[cc * EPI_STRIDE + i];
            }
            part[(0 * 128 + i) * 4 + t] = s0;
            part[(1 * 128 + i) * 4 + t] = s1;
            part[(2 * 128 + i) * 4 + t] = s2;
        }
        __syncthreads();
        // stage 2: 384 threads; f32x4 partial read + reduce + atomic
        if (tid < 384) {
            const int v = tid >> 7, i = tid & 127;
            f32x4 pp = *(const f32x4*)(part + ((size_t)v * 128 + i) * 4);
            float sum = (pp[0] + pp[1]) + (pp[2] + pp[3]);
            const int s = sBase0 + (i >> 6) * 128 + p * 64 + (i & 63);
            if (v == 0)      atomicAdd(&ssq[(size_t)bn * 512 + s], sum);
            else if (v == 1) atomicAdd(&dotb[((size_t)bn * 2 + 0) * 512 + s], sum);
            else             atomicAdd(&dotb[((size_t)bn * 2 + 1) * 512 + s], sum);
        }
    }
}

// ---------------------------------------------------------------------------
// Softmax per (b,n): score = rsqrt(ssq/512+eps)*dot. Mask read inline (raw),
// mode from flag[1].
// ---------------------------------------------------------------------------
__global__ __launch_bounds__(512) void softmax_slice(const float* __restrict__ ssq,
                                                     const float* __restrict__ dot,
                                                     const void* __restrict__ mraw,
                                                     float* __restrict__ pbuf,
                                                     void* __restrict__ out,
                                                     const int* __restrict__ flag,
                                                     int b0) {
    const int bn = b0 * 4 + blockIdx.x;
    const int b = bn >> 2;
    const int tid = threadIdx.x;          // = s
    const int wave = tid >> 6, lane = tid & 63;
    const int is_f32 = flag[0];
    const int mode = flag[1];
    __shared__ float red[32];

    float sq = ssq[(size_t)bn * 512 + tid];
    float rms = rsqrtf(sq * (1.0f / ND) + 1e-6f);
    const int mi = b * NS + tid;
    int masked;
    if (mode == 3)      masked = (((const unsigned short*)mraw)[mi] != 0);
    else if (mode == 1) masked = (((const unsigned char*)mraw)[mi] != 0);
    else if (mode == 0) masked = (((const unsigned int*)mraw)[mi] != 0u);
    else                masked = (((const unsigned int*)mraw)[2 * mi] != 0u);
    float ninf = -__builtin_inff();
    float v0 = masked ? ninf : dot[((size_t)bn * 2 + 0) * 512 + tid] * rms;
    float v1 = masked ? ninf : dot[((size_t)bn * 2 + 1) * 512 + tid] * rms;

    float m0 = v0, m1 = v1;
#pragma unroll
    for (int off = 1; off < 64; off <<= 1) {
        m0 = fmaxf(m0, __shfl_xor(m0, off));
        m1 = fmaxf(m1, __shfl_xor(m1, off));
    }
    if (lane == 0) { red[wave] = m0; red[8 + wave] = m1; }
    __syncthreads();
    m0 = red[0]; m1 = red[8];
#pragma unroll
    for (int w = 1; w < 8; ++w) { m0 = fmaxf(m0, red[w]); m1 = fmaxf(m1, red[8 + w]); }
    float e0 = __expf(v0 - m0), e1 = __expf(v1 - m1);
    float su0 = e0, su1 = e1;
#pragma unroll
    for (int off = 1; off < 64; off <<= 1) {
        su0 += __shfl_xor(su0, off);
        su1 += __shfl_xor(su1, off);
    }
    if (lane == 0) { red[16 + wave] = su0; red[24 + wave] = su1; }
    __syncthreads();
    float t0 = 0.f, t1 = 0.f;
#pragma unroll
    for (int w = 0; w < 8; ++w) { t0 += red[16 + w]; t1 += red[24 + w]; }
    float p0 = e0 / t0, p1 = e1 / t1;

    pbuf[((size_t)bn * 2 + 0) * 512 + tid] = p0;
    pbuf[((size_t)bn * 2 + 1) * 512 + tid] = p1;
    size_t abase = 262144u + (size_t)bn * 1024 + tid;
    store_out(out, is_f32, abase, p0);
    store_out(out, is_f32, abase + 512, p1);
}

// ---------------------------------------------------------------------------
// h~: parallel version. Grid (BSLICE, 8 d-chunks), 512 threads.
// ---------------------------------------------------------------------------
__global__ __launch_bounds__(512) void htilde_kernel(const unsigned short* __restrict__ hspHi,
                                                     const float* __restrict__ pbuf,
                                                     unsigned short* __restrict__ hHi,
                                                     unsigned short* __restrict__ hLo,
                                                     int b0) {
    __shared__ float pl[8][512];          // 16 KB probs
    __shared__ float red[8][64][8];       // 16 KB partials [slane][d][h]
    const int bl = blockIdx.x;
    const int bG = b0 + bl;
    const int d0 = blockIdx.y * 64;
    const int tid = threadIdx.x;
#pragma unroll
    for (int k = 0; k < 8; ++k) {
        const int j = tid + k * 512;
        const int h = j >> 9, s = j & 511;
        pl[h][s] = pbuf[((size_t)(bG * 4 + (h >> 1)) * 2 + (h & 1)) * 512 + s];
    }
    __syncthreads();

    const int dl = tid & 63, sl = tid >> 6;
    const unsigned short* hb = hspHi + (size_t)bl * 512 * 512 + d0 + dl;
    float acc[8];
#pragma unroll
    for (int h = 0; h < 8; ++h) acc[h] = 0.f;
#pragma unroll 4
    for (int i = 0; i < 64; ++i) {
        const int s = i * 8 + sl;
        float hv = b2f(hb[(size_t)s * 512]);
#pragma unroll
        for (int h = 0; h < 8; ++h) acc[h] = fmaf(pl[h][s], hv, acc[h]);
    }
#pragma unroll
    for (int h = 0; h < 8; ++h) red[sl][dl][h] = acc[h];
    __syncthreads();

    const int dl2 = tid >> 3, h2 = tid & 7;
    float v = 0.f;
#pragma unroll
    for (int s2 = 0; s2 < 8; ++s2) v += red[s2][dl2][h2];
    const int row = (h2 >> 1) * 128 + bG * 2 + (h2 & 1);
    unsigned short hv = f2b(v);
    hHi[(size_t)row * 512 + d0 + dl2] = hv;
    hLo[(size_t)row * 512 + d0 + dl2] = f2b(v - b2f(hv));
}

// gemm_out K-split: grid (4 n, 4 e-tiles, 4 k-chunks) -> atomicAdd fp32 outF.
__global__ __launch_bounds__(256) void gemm_out_ks(const unsigned short* __restrict__ hHi,
                                                   const unsigned short* __restrict__ hLo,
                                                   const unsigned short* __restrict__ wvHi,
                                                   float* __restrict__ outF) {
    __shared__ __align__(16) unsigned short AsH[128 * 32];
    __shared__ __align__(16) unsigned short AsL[128 * 32];
    __shared__ __align__(16) unsigned short Bs[128 * 32];
    const int n = blockIdx.x;
    const int m0 = n * 128, n0 = blockIdx.y * 128;
    const int kt0 = blockIdx.z * 4;
    const int tid = threadIdx.x;
    f32x4 acc[4][4];
    mfma2_tile(hHi, hLo, wvHi + (size_t)n * 512 * 512, AsH, AsL, Bs, m0, n0, tid, kt0, kt0 + 4, acc);

    const int lane = tid & 63, wave = tid >> 6;
    const int wr = wave >> 1, wc = wave & 1;
    const int lr = lane & 15, lq = lane >> 4;
#pragma unroll
    for (int ti = 0; ti < 4; ++ti)
#pragma unroll
        for (int tj = 0; tj < 4; ++tj)
#pragma unroll
            for (int r = 0; r < 4; ++r) {
                const int row = m0 + wr * 64 + ti * 16 + lq * 4 + r;   // n*128 + b*2+g
                const int e = n0 + wc * 64 + tj * 16 + lr;
                atomicAdd(&outF[(size_t)row * 512 + e], acc[ti][tj][r]);
            }
}

// outF rows [n][b*2+g] -> out_tokens rows (b*8+n*2+g)
__global__ __launch_bounds__(256) void out_final_kernel(const float* __restrict__ outF,
                                                        void* __restrict__ out,
                                                        const int* __restrict__ flag) {
    const size_t i = (size_t)blockIdx.x * 256 + threadIdx.x;   // grid 1024
    const int row = (int)(i >> 9), e = (int)(i & 511);
    const int n = row >> 7, rl = row & 127;
    const int b = rl >> 1, g = rl & 1;
    store_out(out, flag[0], (size_t)(b * 8 + n * 2 + g) * 512 + e, outF[i]);
}

// ---------------------------------------------------------------------------
extern "C" void kernel_launch(void* const* d_in, const int* in_sizes, int n_in,
                              void* d_out, int out_size, void* d_ws, size_t ws_size,
                              hipStream_t stream) {
    (void)in_sizes; (void)n_in; (void)out_size; (void)ws_size;
    const void* target = d_in[0];   // [64,8,512]
    const void* hist   = d_in[1];   // [64,512,512]
    const void* mraw   = d_in[2];   // [64,512] bool-ish
    const void* Wq     = d_in[3];   // [512,512]
    const void* Wk     = d_in[4];   // [2048,512]
    const void* Wv     = d_in[5];   // [2048,512]
    const void* qnw    = d_in[6];   // [512]
    const void* knw    = d_in[7];   // [512]

    char* w = (char*)d_ws;
    unsigned short* hspHi = (unsigned short*)(w + HSP_HI);
    unsigned short* wkHi  = (unsigned short*)(w + WKH_B);
    unsigned short* wvHi  = (unsigned short*)(w + WVH_B);
    unsigned short* tHi   = (unsigned short*)(w + THI_B);
    unsigned short* tLo   = (unsigned short*)(w + TLO_B);
    unsigned short* qwHi  = (unsigned short*)(w + QWH_B);
    unsigned short* qwLo  = (unsigned short*)(w + QWL_B);
    float* qp    = (float*)(w + QP_B);
    float* dotb  = (float*)(w + DOT_B);
    float* outF  = (float*)(w + OUTF_B);
    float* ssq   = (float*)(w + SSQ_B);
    float* pbuf  = (float*)(w + PBUF_B);
    float* qpF   = (float*)(w + QPF_B);
    unsigned short* hHi  = (unsigned short*)(w + HH_B);
    unsigned short* hLo  = (unsigned short*)(w + HL_B);
    int* flag = (int*)(w + FLAG_B);

    static bool attr_set = false;
    if (!attr_set) {
        (void)hipFuncSetAttribute(reinterpret_cast<const void*>(&gemm_ssq8),
                                  hipFuncAttributeMaxDynamicSharedMemorySize, 131072);
        attr_set = true;
    }

    scan_zero_kernel<<<2 + ZERO_CNT / 256, 256, 0, stream>>>(
        (const unsigned short*)hist, mraw, flag, qp);
    prep_kernel<<<1280, 256, 0, stream>>>(target, Wq, Wk, Wv, tHi, tLo, qwHi, qwLo,
                                          wkHi, wvHi, flag);

    gemm3_ks<<<dim3(4, 4, 4), 256, 0, stream>>>(tHi, tLo, qwHi, qwLo, qp);
    rmsnorm_qperm<<<NB * NT, 64, 0, stream>>>(qp, qnw, knw, qpF, flag);

    for (int sl = 0; sl < NSLICE; ++sl) {
        const int b0 = sl * BSLICE;
        presplit_hist_kernel<<<4096, 256, 0, stream>>>(hist, hspHi, flag,
                                                       (long long)sl * BSLICE * 512 * 512);
        gemm_ssq8<<<dim3(64, 8), 512, 131072, stream>>>(hspHi, wkHi, qpF, ssq, dotb, b0);
        softmax_slice<<<BSLICE * NKV, 512, 0, stream>>>(ssq, dotb, mraw, pbuf, d_out, flag, b0);
        htilde_kernel<<<dim3(BSLICE, 8), 512, 0, stream>>>(hspHi, pbuf, hHi, hLo, b0);
    }
    gemm_out_ks<<<dim3(4, 4, 4), 256, 0, stream>>>(hHi, hLo, wvHi, outF);
    out_final_kernel<<<1024, 256, 0, stream>>>(outF, d_out, flag);
}